// Round 1
// baseline (385.445 us; speedup 1.0000x reference)
//
#include <hip/hip_runtime.h>
#include <hip/hip_bf16.h>

#define NROWS 65536
#define DIM   256
#define NCLS  1000
#define CPAD  1024

typedef __attribute__((ext_vector_type(8))) short bf16x8;   // 8 bf16 = 4 VGPR
typedef __attribute__((ext_vector_type(4))) float f32x4;    // MFMA C/D

// RTNE float -> bf16 bit pattern (finite inputs only)
__device__ inline unsigned short f2bf(float x) {
    unsigned int u = __builtin_bit_cast(unsigned int, x);
    unsigned int lsb = (u >> 16) & 1u;
    u += 0x7fffu + lsb;
    return (unsigned short)(u >> 16);
}

// K1: one wave per row: L2-normalize (clamp 1e-12), store bf16 e,
// atomic-accumulate fp32 class sums + counts.
__global__ __launch_bounds__(256) void k_norm_acc(
    const float* __restrict__ emb, const int* __restrict__ labels,
    unsigned short* __restrict__ e, float* __restrict__ sums,
    float* __restrict__ counts)
{
    int gid  = blockIdx.x * 256 + threadIdx.x;
    int row  = gid >> 6;
    int lane = gid & 63;
    float4 v = ((const float4*)(emb + (size_t)row * DIM))[lane];
    float ss = v.x*v.x + v.y*v.y + v.z*v.z + v.w*v.w;
    #pragma unroll
    for (int off = 1; off < 64; off <<= 1) ss += __shfl_xor(ss, off);
    float inv = 1.0f / fmaxf(sqrtf(ss), 1e-12f);
    v.x *= inv; v.y *= inv; v.z *= inv; v.w *= inv;
    ushort4 u;
    u.x = f2bf(v.x); u.y = f2bf(v.y); u.z = f2bf(v.z); u.w = f2bf(v.w);
    ((ushort4*)(e + (size_t)row * DIM))[lane] = u;
    int lab = labels[row];
    float* sp = sums + (size_t)lab * DIM + lane * 4;
    atomicAdd(sp + 0, v.x);
    atomicAdd(sp + 1, v.y);
    atomicAdd(sp + 2, v.z);
    atomicAdd(sp + 3, v.w);
    if (lane == 0) atomicAdd(counts + lab, 1.0f);
}

// K2: one wave per class (padded to 1024): center = sum/max(cnt,1);
// fold 1/max(||center||,1e-8) into it; store bf16. Padded rows -> 0.
__global__ __launch_bounds__(256) void k_centers(
    const float* __restrict__ sums, const float* __restrict__ counts,
    unsigned short* __restrict__ cs)
{
    int gid  = blockIdx.x * 256 + threadIdx.x;
    int c    = gid >> 6;          // wave-uniform
    int lane = gid & 63;
    float4 v = make_float4(0.f, 0.f, 0.f, 0.f);
    if (c < NCLS) {
        v = ((const float4*)(sums + (size_t)c * DIM))[lane];
        float ic = 1.0f / fmaxf(counts[c], 1.0f);
        v.x *= ic; v.y *= ic; v.z *= ic; v.w *= ic;
        float ss = v.x*v.x + v.y*v.y + v.z*v.z + v.w*v.w;
        #pragma unroll
        for (int off = 1; off < 64; off <<= 1) ss += __shfl_xor(ss, off);
        float sc = 1.0f / fmaxf(sqrtf(ss), 1e-8f);
        v.x *= sc; v.y *= sc; v.z *= sc; v.w *= sc;
    }
    ushort4 u;
    u.x = f2bf(v.x); u.y = f2bf(v.y); u.z = f2bf(v.z); u.w = f2bf(v.w);
    ((ushort4*)(cs + (size_t)c * DIM))[lane] = u;
}

// K3: bf16 MFMA GEMM-BT + fused loss epilogue.
// Block = 256 thr (4 waves, 2x2), 128 rows x (loop over 8 class tiles of 128).
// BK=64 staged in LDS, LDK=72 pad (conflict-free ds_read_b128 frags).
#define TMB 128
#define TCB 128
#define LDK 72

__global__ __launch_bounds__(256) void k_loss_mfma(
    const unsigned short* __restrict__ e, const unsigned short* __restrict__ cs,
    const int* __restrict__ labels, float* __restrict__ acc)
{
    __shared__ __align__(16) unsigned short a_s[TMB * LDK];
    __shared__ __align__(16) unsigned short b_s[TCB * LDK];
    __shared__ float negsum_s[2][TMB];
    __shared__ float slab_s[TMB];
    __shared__ int   lab_s[TMB];
    __shared__ float red_s[4];

    const int tid  = threadIdx.x;
    const int row0 = blockIdx.x * TMB;
    const int wave = tid >> 6, lane = tid & 63;
    const int wm = wave >> 1, wn = wave & 1;   // 2x2 wave grid, wave tile 64x64
    const int l16 = lane & 15, q = lane >> 4;

    if (tid < TMB) {
        lab_s[tid]  = labels[row0 + tid];
        slab_s[tid] = 0.0f;
    }

    float negp[4][4];   // per-lane sum of relu(1-s)^2 over its cols; [mi][reg]
    #pragma unroll
    for (int mi = 0; mi < 4; ++mi)
        #pragma unroll
        for (int rg = 0; rg < 4; ++rg) negp[mi][rg] = 0.0f;

    for (int cb = 0; cb < CPAD / TCB; ++cb) {
        f32x4 accf[4][4] = {};   // zero each class tile
        for (int kc = 0; kc < DIM / 64; ++kc) {
            __syncthreads();     // protect LDS tiles from previous readers
            #pragma unroll
            for (int i = 0; i < 4; ++i) {        // 1024 x 16B chunks per tile
                int idx = tid + i * 256;
                int r   = idx >> 3;
                int c8  = (idx & 7) * 8;
                *(uint4*)&a_s[r * LDK + c8] =
                    *(const uint4*)&e[(size_t)(row0 + r) * DIM + kc * 64 + c8];
                *(uint4*)&b_s[r * LDK + c8] =
                    *(const uint4*)&cs[(size_t)(cb * TCB + r) * DIM + kc * 64 + c8];
            }
            __syncthreads();
            #pragma unroll
            for (int kk = 0; kk < 2; ++kk) {
                bf16x8 af[4], bfr[4];
                #pragma unroll
                for (int mi = 0; mi < 4; ++mi)   // A[m=l16][k=q*8+j]
                    af[mi] = *(const bf16x8*)&a_s[(wm*64 + mi*16 + l16) * LDK + kk*32 + q*8];
                #pragma unroll
                for (int ni = 0; ni < 4; ++ni)   // B^T[n=l16][k=q*8+j]
                    bfr[ni] = *(const bf16x8*)&b_s[(wn*64 + ni*16 + l16) * LDK + kk*32 + q*8];
                #pragma unroll
                for (int mi = 0; mi < 4; ++mi)
                    #pragma unroll
                    for (int ni = 0; ni < 4; ++ni)
                        accf[mi][ni] = __builtin_amdgcn_mfma_f32_16x16x32_bf16(
                            af[mi], bfr[ni], accf[mi][ni], 0, 0, 0);
            }
        }
        // epilogue for this class tile: C/D col = l16, row = q*4 + reg
        #pragma unroll
        for (int mi = 0; mi < 4; ++mi) {
            #pragma unroll
            for (int rg = 0; rg < 4; ++rg) {
                int rloc = wm*64 + mi*16 + q*4 + rg;
                int lab  = lab_s[rloc];
                #pragma unroll
                for (int ni = 0; ni < 4; ++ni) {
                    int c   = cb * TCB + wn*64 + ni*16 + l16;
                    float s = accf[mi][ni][rg];
                    if (c < NCLS) {
                        float t = fmaxf(1.0f - s, 0.0f);
                        negp[mi][rg] += t * t;
                        if (c == lab) slab_s[rloc] = s;   // unique writer per row
                    }
                }
            }
        }
    }

    // reduce neg partials across the 16 lanes sharing a row (same q)
    #pragma unroll
    for (int mi = 0; mi < 4; ++mi) {
        #pragma unroll
        for (int rg = 0; rg < 4; ++rg) {
            float v = negp[mi][rg];
            #pragma unroll
            for (int off = 8; off >= 1; off >>= 1) v += __shfl_down(v, off, 16);
            if (l16 == 0) negsum_s[wn][wm*64 + mi*16 + q*4 + rg] = v;
        }
    }
    __syncthreads();

    // per-row loss, block reduce, one atomic per block
    float part = 0.0f;
    if (tid < TMB) {
        float ns = negsum_s[0][tid] + negsum_s[1][tid];
        float sl = slab_s[tid];
        float t  = fmaxf(1.0f - sl, 0.0f);
        part = (sl - 1.0f) * (sl - 1.0f) + (ns - t * t) * (1.0f / 999.0f);
    }
    #pragma unroll
    for (int off = 32; off >= 1; off >>= 1) part += __shfl_down(part, off, 64);
    if (lane == 0) red_s[wave] = part;
    __syncthreads();
    if (tid == 0) atomicAdd(acc, red_s[0] + red_s[1] + red_s[2] + red_s[3]);
}

__global__ void k_final(const float* __restrict__ acc, float* __restrict__ out)
{
    if (threadIdx.x == 0) out[0] = acc[0] * (1.0f / (float)NROWS);
}

extern "C" void kernel_launch(void* const* d_in, const int* in_sizes, int n_in,
                              void* d_out, int out_size, void* d_ws, size_t ws_size,
                              hipStream_t stream)
{
    const float* emb    = (const float*)d_in[0];
    const int*   labels = (const int*)d_in[1];
    float*       out    = (float*)d_out;
    char*        ws     = (char*)d_ws;

    const size_t OFF_SUM = (size_t)NROWS * DIM * 2;           // e_bf16: 32 MB
    const size_t OFF_CNT = OFF_SUM + (size_t)CPAD * DIM * 4;  // sums: 1 MB
    const size_t OFF_ACC = OFF_CNT + 4096;                    // counts: 4 KB
    const size_t OFF_CS  = OFF_ACC + 16;                      // acc: 16 B

    unsigned short* e      = (unsigned short*)ws;
    float*          sums   = (float*)(ws + OFF_SUM);
    float*          counts = (float*)(ws + OFF_CNT);
    float*          acc    = (float*)(ws + OFF_ACC);
    unsigned short* cs     = (unsigned short*)(ws + OFF_CS);

    // zero sums + counts + acc (ws is re-poisoned before every timed call)
    hipMemsetAsync(ws + OFF_SUM, 0, (size_t)CPAD * DIM * 4 + 4096 + 16, stream);

    k_norm_acc <<<NROWS / 4, 256, 0, stream>>>(emb, labels, e, sums, counts);
    k_centers  <<<CPAD  / 4, 256, 0, stream>>>(sums, counts, cs);
    k_loss_mfma<<<NROWS / TMB, 256, 0, stream>>>(e, cs, labels, acc);
    k_final    <<<1, 64, 0, stream>>>(acc, out);
}

// Round 2
// 273.477 us; speedup vs baseline: 1.4094x; 1.4094x over previous
//
#include <hip/hip_runtime.h>
#include <hip/hip_bf16.h>

#define NROWS 65536
#define DIM   256
#define NCLS  1000
#define CPAD  1024

typedef __attribute__((ext_vector_type(8))) short bf16x8;   // 8 bf16 = 4 VGPR
typedef __attribute__((ext_vector_type(4))) float f32x4;    // MFMA C/D

// RTNE float -> bf16 bit pattern (finite inputs only)
__device__ inline unsigned short f2bf(float x) {
    unsigned int u = __builtin_bit_cast(unsigned int, x);
    unsigned int lsb = (u >> 16) & 1u;
    u += 0x7fffu + lsb;
    return (unsigned short)(u >> 16);
}

__device__ inline float bf2f(unsigned short u) {
    unsigned int v = ((unsigned int)u) << 16;
    return __builtin_bit_cast(float, v);
}

// K1: one wave per row: L2-normalize (clamp 1e-12), store bf16 e,
// count labels via global atomic (65K atomics total — cheap).
__global__ __launch_bounds__(256) void k_norm_acc(
    const float* __restrict__ emb, const int* __restrict__ labels,
    unsigned short* __restrict__ e, float* __restrict__ counts)
{
    int gid  = blockIdx.x * 256 + threadIdx.x;
    int row  = gid >> 6;
    int lane = gid & 63;
    float4 v = ((const float4*)(emb + (size_t)row * DIM))[lane];
    float ss = v.x*v.x + v.y*v.y + v.z*v.z + v.w*v.w;
    #pragma unroll
    for (int off = 1; off < 64; off <<= 1) ss += __shfl_xor(ss, off);
    float inv = 1.0f / fmaxf(sqrtf(ss), 1e-12f);
    v.x *= inv; v.y *= inv; v.z *= inv; v.w *= inv;
    ushort4 u;
    u.x = f2bf(v.x); u.y = f2bf(v.y); u.z = f2bf(v.z); u.w = f2bf(v.w);
    ((ushort4*)(e + (size_t)row * DIM))[lane] = u;
    if (lane == 0) atomicAdd(counts + labels[row], 1.0f);
}

// K2: class sums via LDS bins, no global atomics.
// Grid 256 blocks = 16 dchunks x 16 rowsplits. Block: bins[1000][16] fp32
// (62.5 KB LDS, 2 blocks/CU), 4096 rows x 16 dims, ds_add_f32 (<=2-way banks).
// Flush -> partial[rs][1000][256] (plain stores).
#define RSPLIT 16
#define DCH    16
#define RPB    (NROWS / RSPLIT)   // 4096

__global__ __launch_bounds__(256) void k_class_sum(
    const unsigned short* __restrict__ e, const int* __restrict__ labels,
    float* __restrict__ partial)
{
    __shared__ float bins[NCLS * DCH];   // 62.5 KB
    __shared__ int   labs[RPB];          // 16 KB
    const int tid = threadIdx.x;
    const int dc  = blockIdx.x & 15;
    const int rs  = blockIdx.x >> 4;
    const int row0 = rs * RPB;

    for (int i = tid; i < NCLS * DCH; i += 256) bins[i] = 0.0f;
    #pragma unroll
    for (int k = 0; k < RPB / 256; ++k)
        labs[tid + k * 256] = labels[row0 + tid + k * 256];
    __syncthreads();

    const int j    = tid & 15;          // dim within chunk
    const int rsub = tid >> 4;          // 0..15: 16 rows per iteration
    const unsigned short* ebase = e + (size_t)row0 * DIM + dc * DCH + j;

    for (int i = 0; i < RPB / 16; i += 8) {       // 256 iters, unroll 8
        float v[8]; int lb[8];
        #pragma unroll
        for (int u = 0; u < 8; ++u) {             // 8 outstanding loads
            int r = (i + u) * 16 + rsub;
            v[u]  = bf2f(ebase[(size_t)r * DIM]);
            lb[u] = labs[r];
        }
        #pragma unroll
        for (int u = 0; u < 8; ++u)
            atomicAdd(&bins[lb[u] * DCH + j], v[u]);
    }
    __syncthreads();

    // flush: coalesced 64B chunks
    for (int i = tid; i < NCLS * DCH; i += 256) {
        int c = i >> 4, jj = i & 15;
        partial[(size_t)rs * (NCLS * DIM) + c * DIM + dc * DCH + jj] = bins[i];
    }
}

// K3: one wave per class (padded to 1024): reduce 16 partials,
// center = sum/max(cnt,1); fold 1/max(||center||,1e-8); store bf16.
__global__ __launch_bounds__(256) void k_centers(
    const float* __restrict__ partial, const float* __restrict__ counts,
    unsigned short* __restrict__ cs)
{
    int gid  = blockIdx.x * 256 + threadIdx.x;
    int c    = gid >> 6;          // wave-uniform
    int lane = gid & 63;
    float4 v = make_float4(0.f, 0.f, 0.f, 0.f);
    if (c < NCLS) {
        #pragma unroll
        for (int rs = 0; rs < RSPLIT; ++rs) {
            float4 p = ((const float4*)(partial + (size_t)rs * (NCLS * DIM)
                                        + (size_t)c * DIM))[lane];
            v.x += p.x; v.y += p.y; v.z += p.z; v.w += p.w;
        }
        float ic = 1.0f / fmaxf(counts[c], 1.0f);
        v.x *= ic; v.y *= ic; v.z *= ic; v.w *= ic;
        float ss = v.x*v.x + v.y*v.y + v.z*v.z + v.w*v.w;
        #pragma unroll
        for (int off = 1; off < 64; off <<= 1) ss += __shfl_xor(ss, off);
        float sc = 1.0f / fmaxf(sqrtf(ss), 1e-8f);
        v.x *= sc; v.y *= sc; v.z *= sc; v.w *= sc;
    }
    ushort4 u;
    u.x = f2bf(v.x); u.y = f2bf(v.y); u.z = f2bf(v.z); u.w = f2bf(v.w);
    ((ushort4*)(cs + (size_t)c * DIM))[lane] = u;
}

// K4: bf16 MFMA GEMM-BT + fused loss epilogue (unchanged from R1).
#define TMB 128
#define TCB 128
#define LDK 72

__global__ __launch_bounds__(256) void k_loss_mfma(
    const unsigned short* __restrict__ e, const unsigned short* __restrict__ cs,
    const int* __restrict__ labels, float* __restrict__ acc)
{
    __shared__ __align__(16) unsigned short a_s[TMB * LDK];
    __shared__ __align__(16) unsigned short b_s[TCB * LDK];
    __shared__ float negsum_s[2][TMB];
    __shared__ float slab_s[TMB];
    __shared__ int   lab_s[TMB];
    __shared__ float red_s[4];

    const int tid  = threadIdx.x;
    const int row0 = blockIdx.x * TMB;
    const int wave = tid >> 6, lane = tid & 63;
    const int wm = wave >> 1, wn = wave & 1;   // 2x2 wave grid, wave tile 64x64
    const int l16 = lane & 15, q = lane >> 4;

    if (tid < TMB) {
        lab_s[tid]  = labels[row0 + tid];
        slab_s[tid] = 0.0f;
    }

    float negp[4][4];
    #pragma unroll
    for (int mi = 0; mi < 4; ++mi)
        #pragma unroll
        for (int rg = 0; rg < 4; ++rg) negp[mi][rg] = 0.0f;

    for (int cb = 0; cb < CPAD / TCB; ++cb) {
        f32x4 accf[4][4] = {};
        for (int kc = 0; kc < DIM / 64; ++kc) {
            __syncthreads();
            #pragma unroll
            for (int i = 0; i < 4; ++i) {
                int idx = tid + i * 256;
                int r   = idx >> 3;
                int c8  = (idx & 7) * 8;
                *(uint4*)&a_s[r * LDK + c8] =
                    *(const uint4*)&e[(size_t)(row0 + r) * DIM + kc * 64 + c8];
                *(uint4*)&b_s[r * LDK + c8] =
                    *(const uint4*)&cs[(size_t)(cb * TCB + r) * DIM + kc * 64 + c8];
            }
            __syncthreads();
            #pragma unroll
            for (int kk = 0; kk < 2; ++kk) {
                bf16x8 af[4], bfr[4];
                #pragma unroll
                for (int mi = 0; mi < 4; ++mi)
                    af[mi] = *(const bf16x8*)&a_s[(wm*64 + mi*16 + l16) * LDK + kk*32 + q*8];
                #pragma unroll
                for (int ni = 0; ni < 4; ++ni)
                    bfr[ni] = *(const bf16x8*)&b_s[(wn*64 + ni*16 + l16) * LDK + kk*32 + q*8];
                #pragma unroll
                for (int mi = 0; mi < 4; ++mi)
                    #pragma unroll
                    for (int ni = 0; ni < 4; ++ni)
                        accf[mi][ni] = __builtin_amdgcn_mfma_f32_16x16x32_bf16(
                            af[mi], bfr[ni], accf[mi][ni], 0, 0, 0);
            }
        }
        #pragma unroll
        for (int mi = 0; mi < 4; ++mi) {
            #pragma unroll
            for (int rg = 0; rg < 4; ++rg) {
                int rloc = wm*64 + mi*16 + q*4 + rg;
                int lab  = lab_s[rloc];
                #pragma unroll
                for (int ni = 0; ni < 4; ++ni) {
                    int c   = cb * TCB + wn*64 + ni*16 + l16;
                    float s = accf[mi][ni][rg];
                    if (c < NCLS) {
                        float t = fmaxf(1.0f - s, 0.0f);
                        negp[mi][rg] += t * t;
                        if (c == lab) slab_s[rloc] = s;
                    }
                }
            }
        }
    }

    #pragma unroll
    for (int mi = 0; mi < 4; ++mi) {
        #pragma unroll
        for (int rg = 0; rg < 4; ++rg) {
            float v = negp[mi][rg];
            #pragma unroll
            for (int off = 8; off >= 1; off >>= 1) v += __shfl_down(v, off, 16);
            if (l16 == 0) negsum_s[wn][wm*64 + mi*16 + q*4 + rg] = v;
        }
    }
    __syncthreads();

    float part = 0.0f;
    if (tid < TMB) {
        float ns = negsum_s[0][tid] + negsum_s[1][tid];
        float sl = slab_s[tid];
        float t  = fmaxf(1.0f - sl, 0.0f);
        part = (sl - 1.0f) * (sl - 1.0f) + (ns - t * t) * (1.0f / 999.0f);
    }
    #pragma unroll
    for (int off = 32; off >= 1; off >>= 1) part += __shfl_down(part, off, 64);
    if (lane == 0) red_s[wave] = part;
    __syncthreads();
    if (tid == 0) atomicAdd(acc, red_s[0] + red_s[1] + red_s[2] + red_s[3]);
}

__global__ void k_final(const float* __restrict__ acc, float* __restrict__ out)
{
    if (threadIdx.x == 0) out[0] = acc[0] * (1.0f / (float)NROWS);
}

extern "C" void kernel_launch(void* const* d_in, const int* in_sizes, int n_in,
                              void* d_out, int out_size, void* d_ws, size_t ws_size,
                              hipStream_t stream)
{
    const float* emb    = (const float*)d_in[0];
    const int*   labels = (const int*)d_in[1];
    float*       out    = (float*)d_out;
    char*        ws     = (char*)d_ws;

    const size_t OFF_PART = (size_t)NROWS * DIM * 2;                    // e: 32 MB
    const size_t OFF_CNT  = OFF_PART + (size_t)RSPLIT * NCLS * DIM * 4; // partial: 16 MB
    const size_t OFF_ACC  = OFF_CNT + 4096;                             // counts: 4 KB
    const size_t OFF_CS   = OFF_ACC + 16;                               // acc: 16 B

    unsigned short* e       = (unsigned short*)ws;
    float*          partial = (float*)(ws + OFF_PART);
    float*          counts  = (float*)(ws + OFF_CNT);
    float*          acc     = (float*)(ws + OFF_ACC);
    unsigned short* cs      = (unsigned short*)(ws + OFF_CS);

    // zero counts + acc only (partial is fully overwritten by k_class_sum)
    hipMemsetAsync(ws + OFF_CNT, 0, 4096 + 16, stream);

    k_norm_acc <<<NROWS / 4, 256, 0, stream>>>(emb, labels, e, counts);
    k_class_sum<<<RSPLIT * 16, 256, 0, stream>>>(e, labels, partial);
    k_centers  <<<CPAD / 4, 256, 0, stream>>>(partial, counts, cs);
    k_loss_mfma<<<NROWS / TMB, 256, 0, stream>>>(e, cs, labels, acc);
    k_final    <<<1, 64, 0, stream>>>(acc, out);
}

// Round 3
// 261.880 us; speedup vs baseline: 1.4718x; 1.0443x over previous
//
#include <hip/hip_runtime.h>
#include <hip/hip_bf16.h>

#define NROWS 65536
#define DIM   256
#define NCLS  1000
#define CPAD  1024

typedef __attribute__((ext_vector_type(8))) short bf16x8;   // 8 bf16 = 4 VGPR
typedef __attribute__((ext_vector_type(4))) float f32x4;    // MFMA C/D

// RTNE float -> bf16 bit pattern (finite inputs only)
__device__ inline unsigned short f2bf(float x) {
    unsigned int u = __builtin_bit_cast(unsigned int, x);
    unsigned int lsb = (u >> 16) & 1u;
    u += 0x7fffu + lsb;
    return (unsigned short)(u >> 16);
}

__device__ inline float bf2f(unsigned short u) {
    unsigned int v = ((unsigned int)u) << 16;
    return __builtin_bit_cast(float, v);
}

// async global->LDS, 16 B per lane, dst = uniform base + lane*16
__device__ inline void gload_lds16(const void* g, void* l) {
    __builtin_amdgcn_global_load_lds(
        (const __attribute__((address_space(1))) unsigned int*)g,
        (__attribute__((address_space(3))) unsigned int*)l, 16, 0, 0);
}

// K1: one wave per row: L2-normalize (clamp 1e-12), store bf16 e,
// count labels via global atomic (65K atomics total — cheap).
__global__ __launch_bounds__(256) void k_norm_acc(
    const float* __restrict__ emb, const int* __restrict__ labels,
    unsigned short* __restrict__ e, float* __restrict__ counts)
{
    int gid  = blockIdx.x * 256 + threadIdx.x;
    int row  = gid >> 6;
    int lane = gid & 63;
    float4 v = ((const float4*)(emb + (size_t)row * DIM))[lane];
    float ss = v.x*v.x + v.y*v.y + v.z*v.z + v.w*v.w;
    #pragma unroll
    for (int off = 1; off < 64; off <<= 1) ss += __shfl_xor(ss, off);
    float inv = 1.0f / fmaxf(sqrtf(ss), 1e-12f);
    v.x *= inv; v.y *= inv; v.z *= inv; v.w *= inv;
    ushort4 u;
    u.x = f2bf(v.x); u.y = f2bf(v.y); u.z = f2bf(v.z); u.w = f2bf(v.w);
    ((ushort4*)(e + (size_t)row * DIM))[lane] = u;
    if (lane == 0) atomicAdd(counts + labels[row], 1.0f);
}

// K2: class sums via LDS bins (transposed layout bins[j][class]).
// Grid 256 = 16 dchunks x 16 rsplits; 256 thr; thread-per-row:
// each thread handles 16 rows, loading 32 B/row vectorized + coalesced label.
// Atomic bank = (8j + lab) % 32 -> ~2-way (free). Flush coalesced to
// partial[rs][dc][c][16].
#define RSPLIT 16
#define DCH    16
#define RPB    (NROWS / RSPLIT)   // 4096

__global__ __launch_bounds__(256) void k_class_sum(
    const unsigned short* __restrict__ e, const int* __restrict__ labels,
    float* __restrict__ partial)
{
    __shared__ float bins[DCH * NCLS];   // bins[j*NCLS + c], 62.5 KB
    const int tid  = threadIdx.x;
    const int dc   = blockIdx.x & 15;
    const int rs   = blockIdx.x >> 4;
    const int row0 = rs * RPB;

    for (int i = tid; i < DCH * NCLS; i += 256) bins[i] = 0.0f;
    __syncthreads();

    for (int i = 0; i < RPB / 256; i += 4) {      // 16 rows/thread, unroll 4
        uint4 dlo[4], dhi[4]; int lb[4];
        #pragma unroll
        for (int u = 0; u < 4; ++u) {             // 8 dwordx4 + 4 dword in flight
            int r = row0 + (i + u) * 256 + tid;
            const unsigned short* p = e + (size_t)r * DIM + dc * DCH;
            dlo[u] = *(const uint4*)p;
            dhi[u] = *(const uint4*)(p + 8);
            lb[u]  = labels[r];
        }
        #pragma unroll
        for (int u = 0; u < 4; ++u) {
            unsigned int w[8] = {dlo[u].x, dlo[u].y, dlo[u].z, dlo[u].w,
                                 dhi[u].x, dhi[u].y, dhi[u].z, dhi[u].w};
            int c = lb[u];
            #pragma unroll
            for (int jj = 0; jj < 8; ++jj) {
                atomicAdd(&bins[(2*jj    ) * NCLS + c], bf2f((unsigned short)(w[jj] & 0xffffu)));
                atomicAdd(&bins[(2*jj + 1) * NCLS + c], bf2f((unsigned short)(w[jj] >> 16)));
            }
        }
    }
    __syncthreads();

    // flush: partial[((rs*16+dc)*1000 + c)*16 + j], consecutive tid -> contiguous
    for (int i = tid; i < DCH * NCLS; i += 256) {
        int c = i >> 4, j = i & 15;
        partial[(((size_t)rs * 16 + dc) * NCLS + c) * 16 + j] = bins[j * NCLS + c];
    }
}

// K3: one wave per class (padded to 1024): reduce 16 partials,
// center = sum/max(cnt,1); fold 1/max(||center||,1e-8); store bf16.
__global__ __launch_bounds__(256) void k_centers(
    const float* __restrict__ partial, const float* __restrict__ counts,
    unsigned short* __restrict__ cs)
{
    int gid  = blockIdx.x * 256 + threadIdx.x;
    int c    = gid >> 6;          // wave-uniform
    int lane = gid & 63;
    float4 v = make_float4(0.f, 0.f, 0.f, 0.f);
    if (c < NCLS) {
        int dcp = lane >> 2;            // dim chunk this lane's float4 lives in
        int jo  = (lane & 3) * 4;       // offset within chunk
        #pragma unroll
        for (int rs = 0; rs < RSPLIT; ++rs) {
            float4 p = *(const float4*)&partial[
                (((size_t)rs * 16 + dcp) * NCLS + c) * 16 + jo];
            v.x += p.x; v.y += p.y; v.z += p.z; v.w += p.w;
        }
        float ic = 1.0f / fmaxf(counts[c], 1.0f);
        v.x *= ic; v.y *= ic; v.z *= ic; v.w *= ic;
        float ss = v.x*v.x + v.y*v.y + v.z*v.z + v.w*v.w;
        #pragma unroll
        for (int off = 1; off < 64; off <<= 1) ss += __shfl_xor(ss, off);
        float sc = 1.0f / fmaxf(sqrtf(ss), 1e-8f);
        v.x *= sc; v.y *= sc; v.z *= sc; v.w *= sc;
    }
    ushort4 u;
    u.x = f2bf(v.x); u.y = f2bf(v.y); u.z = f2bf(v.z); u.w = f2bf(v.w);
    ((ushort4*)(cs + (size_t)c * DIM))[lane] = u;
}

// K4: bf16 MFMA GEMM-BT + fused loss epilogue.
// Staging via global_load_lds (16 B/lane) with XOR source swizzle:
// LDS slot (row, m) holds global slice m^(row&7); frag reads use the same XOR
// -> 2-way banks (free) while the DMA dst stays lane-linear.
#define TMB 128
#define TCB 128

__global__ __launch_bounds__(256) void k_loss_mfma(
    const unsigned short* __restrict__ e, const unsigned short* __restrict__ cs,
    const int* __restrict__ labels, float* __restrict__ acc)
{
    __shared__ __align__(16) unsigned short a_s[TMB * 64];
    __shared__ __align__(16) unsigned short b_s[TCB * 64];
    __shared__ float negsum_s[2][TMB];
    __shared__ float slab_s[TMB];
    __shared__ int   lab_s[TMB];
    __shared__ float red_s[4];

    const int tid  = threadIdx.x;
    const int row0 = blockIdx.x * TMB;
    const int wave = tid >> 6, lane = tid & 63;
    const int wm = wave >> 1, wn = wave & 1;   // 2x2 wave grid, wave tile 64x64
    const int l16 = lane & 15, q = lane >> 4;

    // staging: lane l -> row (l>>3) of its 8-row chunk, source slice (l&7)^(l>>3)
    const int st_r = lane >> 3;
    const int st_s = (lane & 7) ^ st_r;

    if (tid < TMB) {
        lab_s[tid]  = labels[row0 + tid];
        slab_s[tid] = 0.0f;
    }

    float negp[4][4];
    #pragma unroll
    for (int mi = 0; mi < 4; ++mi)
        #pragma unroll
        for (int rg = 0; rg < 4; ++rg) negp[mi][rg] = 0.0f;

    for (int cb = 0; cb < CPAD / TCB; ++cb) {
        f32x4 accf[4][4] = {};
        for (int kc = 0; kc < DIM / 64; ++kc) {
            __syncthreads();     // previous tile's readers done
            #pragma unroll
            for (int c = 0; c < 4; ++c) {
                int chunk = wave * 4 + c;            // 16 chunks of 8 rows
                int row   = chunk * 8 + st_r;
                gload_lds16(&e [(size_t)(row0    + row) * DIM + kc * 64 + st_s * 8],
                            &a_s[chunk * 512]);
                gload_lds16(&cs[(size_t)(cb*TCB + row) * DIM + kc * 64 + st_s * 8],
                            &b_s[chunk * 512]);
            }
            __syncthreads();     // vmcnt(0) drain + visibility
            #pragma unroll
            for (int kk = 0; kk < 2; ++kk) {
                bf16x8 af[4], bfr[4];
                #pragma unroll
                for (int mi = 0; mi < 4; ++mi) {
                    int rowA = wm*64 + mi*16 + l16;
                    af[mi] = *(const bf16x8*)&a_s[rowA*64 + (((kk*4 + q) ^ (rowA & 7)) * 8)];
                }
                #pragma unroll
                for (int ni = 0; ni < 4; ++ni) {
                    int rowB = wn*64 + ni*16 + l16;
                    bfr[ni] = *(const bf16x8*)&b_s[rowB*64 + (((kk*4 + q) ^ (rowB & 7)) * 8)];
                }
                #pragma unroll
                for (int mi = 0; mi < 4; ++mi)
                    #pragma unroll
                    for (int ni = 0; ni < 4; ++ni)
                        accf[mi][ni] = __builtin_amdgcn_mfma_f32_16x16x32_bf16(
                            af[mi], bfr[ni], accf[mi][ni], 0, 0, 0);
            }
        }
        // epilogue for this class tile: C/D col = l16, row = q*4 + reg
        #pragma unroll
        for (int mi = 0; mi < 4; ++mi) {
            #pragma unroll
            for (int rg = 0; rg < 4; ++rg) {
                int rloc = wm*64 + mi*16 + q*4 + rg;
                int lab  = lab_s[rloc];
                #pragma unroll
                for (int ni = 0; ni < 4; ++ni) {
                    int c   = cb * TCB + wn*64 + ni*16 + l16;
                    float s = accf[mi][ni][rg];
                    if (c < NCLS) {
                        float t = fmaxf(1.0f - s, 0.0f);
                        negp[mi][rg] += t * t;
                        if (c == lab) slab_s[rloc] = s;   // unique writer per row
                    }
                }
            }
        }
    }

    #pragma unroll
    for (int mi = 0; mi < 4; ++mi) {
        #pragma unroll
        for (int rg = 0; rg < 4; ++rg) {
            float v = negp[mi][rg];
            #pragma unroll
            for (int off = 8; off >= 1; off >>= 1) v += __shfl_down(v, off, 16);
            if (l16 == 0) negsum_s[wn][wm*64 + mi*16 + q*4 + rg] = v;
        }
    }
    __syncthreads();

    float part = 0.0f;
    if (tid < TMB) {
        float ns = negsum_s[0][tid] + negsum_s[1][tid];
        float sl = slab_s[tid];
        float t  = fmaxf(1.0f - sl, 0.0f);
        part = (sl - 1.0f) * (sl - 1.0f) + (ns - t * t) * (1.0f / 999.0f);
    }
    #pragma unroll
    for (int off = 32; off >= 1; off >>= 1) part += __shfl_down(part, off, 64);
    if (lane == 0) red_s[wave] = part;
    __syncthreads();
    if (tid == 0) atomicAdd(acc, red_s[0] + red_s[1] + red_s[2] + red_s[3]);
}

__global__ void k_final(const float* __restrict__ acc, float* __restrict__ out)
{
    if (threadIdx.x == 0) out[0] = acc[0] * (1.0f / (float)NROWS);
}

extern "C" void kernel_launch(void* const* d_in, const int* in_sizes, int n_in,
                              void* d_out, int out_size, void* d_ws, size_t ws_size,
                              hipStream_t stream)
{
    const float* emb    = (const float*)d_in[0];
    const int*   labels = (const int*)d_in[1];
    float*       out    = (float*)d_out;
    char*        ws     = (char*)d_ws;

    const size_t OFF_PART = (size_t)NROWS * DIM * 2;                    // e: 32 MB
    const size_t OFF_CNT  = OFF_PART + (size_t)RSPLIT * NCLS * DIM * 4; // partial: 16 MB
    const size_t OFF_ACC  = OFF_CNT + 4096;                             // counts: 4 KB
    const size_t OFF_CS   = OFF_ACC + 16;                               // acc: 16 B

    unsigned short* e       = (unsigned short*)ws;
    float*          partial = (float*)(ws + OFF_PART);
    float*          counts  = (float*)(ws + OFF_CNT);
    float*          acc     = (float*)(ws + OFF_ACC);
    unsigned short* cs      = (unsigned short*)(ws + OFF_CS);

    // zero counts + acc only (partial fully overwritten by k_class_sum)
    hipMemsetAsync(ws + OFF_CNT, 0, 4096 + 16, stream);

    k_norm_acc <<<NROWS / 4, 256, 0, stream>>>(emb, labels, e, counts);
    k_class_sum<<<RSPLIT * 16, 256, 0, stream>>>(e, labels, partial);
    k_centers  <<<CPAD / 4, 256, 0, stream>>>(partial, counts, cs);
    k_loss_mfma<<<NROWS / TMB, 256, 0, stream>>>(e, cs, labels, acc);
    k_final    <<<1, 64, 0, stream>>>(acc, out);
}

// Round 4
// 195.632 us; speedup vs baseline: 1.9703x; 1.3386x over previous
//
#include <hip/hip_runtime.h>
#include <hip/hip_bf16.h>

#define NROWS 65536
#define DIM   256
#define NCLS  1000
#define CPAD  1024

typedef __attribute__((ext_vector_type(8))) short bf16x8;   // 8 bf16 = 4 VGPR
typedef __attribute__((ext_vector_type(4))) float f32x4;    // MFMA C/D

// RTNE float -> bf16 bit pattern (finite inputs only)
__device__ inline unsigned short f2bf(float x) {
    unsigned int u = __builtin_bit_cast(unsigned int, x);
    unsigned int lsb = (u >> 16) & 1u;
    u += 0x7fffu + lsb;
    return (unsigned short)(u >> 16);
}

__device__ inline float bf2f(unsigned short u) {
    unsigned int v = ((unsigned int)u) << 16;
    return __builtin_bit_cast(float, v);
}

// async global->LDS, 16 B per lane, dst = wave-uniform base + lane*16
__device__ inline void gload_lds16(const void* g, void* l) {
    __builtin_amdgcn_global_load_lds(
        (const __attribute__((address_space(1))) unsigned int*)g,
        (__attribute__((address_space(3))) unsigned int*)l, 16, 0, 0);
}

// K1: one wave per row: L2-normalize (clamp 1e-12), store bf16 e,
// label histogram via global uint atomic (65K lane-ops ~ 2 us).
__global__ __launch_bounds__(256) void k_norm_acc(
    const float* __restrict__ emb, const int* __restrict__ labels,
    unsigned short* __restrict__ e, unsigned int* __restrict__ counts)
{
    int gid  = blockIdx.x * 256 + threadIdx.x;
    int row  = gid >> 6;
    int lane = gid & 63;
    float4 v = ((const float4*)(emb + (size_t)row * DIM))[lane];
    float ss = v.x*v.x + v.y*v.y + v.z*v.z + v.w*v.w;
    #pragma unroll
    for (int off = 1; off < 64; off <<= 1) ss += __shfl_xor(ss, off);
    float inv = 1.0f / fmaxf(sqrtf(ss), 1e-12f);
    v.x *= inv; v.y *= inv; v.z *= inv; v.w *= inv;
    ushort4 u;
    u.x = f2bf(v.x); u.y = f2bf(v.y); u.z = f2bf(v.z); u.w = f2bf(v.w);
    ((ushort4*)(e + (size_t)row * DIM))[lane] = u;
    if (lane == 0) atomicAdd(counts + labels[row], 1u);
}

// K2: exclusive prefix scan of counts -> offs, cursor. One block, 1024 thr.
__global__ __launch_bounds__(1024) void k_prefix(
    const unsigned int* __restrict__ counts, unsigned int* __restrict__ offs,
    unsigned int* __restrict__ cursor)
{
    __shared__ unsigned int s[1024];
    int t = threadIdx.x;
    s[t] = (t < NCLS) ? counts[t] : 0u;
    __syncthreads();
    for (int d = 1; d < 1024; d <<= 1) {
        unsigned int v = (t >= d) ? s[t - d] : 0u;
        __syncthreads();
        s[t] += v;
        __syncthreads();
    }
    if (t < NCLS) {
        unsigned int excl = (t == 0) ? 0u : s[t - 1];
        offs[t]   = excl;
        cursor[t] = excl;
    }
}

// K3: scatter row indices into label-sorted order (order within class
// is arrival order — harmless fp32 sum reordering).
__global__ __launch_bounds__(256) void k_scatter(
    const int* __restrict__ labels, unsigned int* __restrict__ cursor,
    int* __restrict__ sidx)
{
    int r = blockIdx.x * 256 + threadIdx.x;
    unsigned int pos = atomicAdd(&cursor[labels[r]], 1u);
    sidx[pos] = r;
}

// K4: atomic-free class sums. One block per class; 256 thr =
// 16 row-slots x 16 dim-chunks; register accumulate; LDS tree reduce.
__global__ __launch_bounds__(256) void k_gather_sum(
    const unsigned short* __restrict__ e, const int* __restrict__ sidx,
    const unsigned int* __restrict__ offs, const unsigned int* __restrict__ counts,
    float* __restrict__ sums)
{
    __shared__ int   sidx_s[256];
    __shared__ float part[16][256];
    const int tid = threadIdx.x;
    const int c   = blockIdx.x;
    const int rs  = tid >> 4;       // row slot 0..15
    const int jc  = tid & 15;       // dim chunk (16 dims = 32 B)
    unsigned int beg = offs[c], cnt = counts[c];

    float a[16];
    #pragma unroll
    for (int k = 0; k < 16; ++k) a[k] = 0.0f;

    for (unsigned int base = 0; base < cnt; base += 256) {
        int m = (int)(cnt - base > 256u ? 256u : cnt - base);
        __syncthreads();
        if (tid < m) sidx_s[tid] = sidx[beg + base + tid];
        __syncthreads();
        for (int u = rs; u < m; u += 16) {
            const unsigned short* p = e + (size_t)sidx_s[u] * DIM + jc * 16;
            uint4 lo = *(const uint4*)p;
            uint4 hi = *(const uint4*)(p + 8);
            unsigned int w[8] = {lo.x, lo.y, lo.z, lo.w, hi.x, hi.y, hi.z, hi.w};
            #pragma unroll
            for (int kk = 0; kk < 8; ++kk) {
                a[2*kk]   += bf2f((unsigned short)(w[kk] & 0xffffu));
                a[2*kk+1] += bf2f((unsigned short)(w[kk] >> 16));
            }
        }
    }
    #pragma unroll
    for (int k = 0; k < 16; ++k) part[rs][jc * 16 + k] = a[k];
    __syncthreads();
    float s = 0.0f;
    #pragma unroll
    for (int r2 = 0; r2 < 16; ++r2) s += part[r2][tid];
    sums[(size_t)c * DIM + tid] = s;
}

// K5: one wave per class (padded to 1024): center = sum/max(cnt,1);
// fold 1/max(||center||,1e-8) into it; store bf16. Padded rows -> 0.
__global__ __launch_bounds__(256) void k_centers(
    const float* __restrict__ sums, const unsigned int* __restrict__ counts,
    unsigned short* __restrict__ cs)
{
    int gid  = blockIdx.x * 256 + threadIdx.x;
    int c    = gid >> 6;          // wave-uniform
    int lane = gid & 63;
    float4 v = make_float4(0.f, 0.f, 0.f, 0.f);
    if (c < NCLS) {
        v = ((const float4*)(sums + (size_t)c * DIM))[lane];
        float ic = 1.0f / fmaxf((float)counts[c], 1.0f);
        v.x *= ic; v.y *= ic; v.z *= ic; v.w *= ic;
        float ss = v.x*v.x + v.y*v.y + v.z*v.z + v.w*v.w;
        #pragma unroll
        for (int off = 1; off < 64; off <<= 1) ss += __shfl_xor(ss, off);
        float sc = 1.0f / fmaxf(sqrtf(ss), 1e-8f);
        v.x *= sc; v.y *= sc; v.z *= sc; v.w *= sc;
    }
    ushort4 u;
    u.x = f2bf(v.x); u.y = f2bf(v.y); u.z = f2bf(v.z); u.w = f2bf(v.w);
    ((ushort4*)(cs + (size_t)c * DIM))[lane] = u;
}

// K6: bf16 MFMA GEMM-BT + fused loss epilogue.
// A (128 rows x K=256) held in registers (loaded once, direct from global);
// B tiles (128 classes x 64 dims) double-buffered in LDS via global_load_lds
// with XOR swizzle; one barrier per 32-MFMA chunk, prefetch in flight across it.
#define TMB 128
#define TCB 128

__global__ __launch_bounds__(256, 2) void k_loss_mfma(
    const unsigned short* __restrict__ e, const unsigned short* __restrict__ cs,
    const int* __restrict__ labels, float* __restrict__ acc)
{
    __shared__ __align__(16) unsigned short b_s[2][TCB * 64];  // 2 x 16 KB
    __shared__ float negsum_s[2][TMB];
    __shared__ float slab_s[TMB];
    __shared__ int   lab_s[TMB];
    __shared__ float red_s[4];

    const int tid  = threadIdx.x;
    const int row0 = blockIdx.x * TMB;
    const int wave = tid >> 6, lane = tid & 63;
    const int wm = wave >> 1, wn = wave & 1;   // 2x2 wave grid, wave tile 64x64
    const int l16 = lane & 15, q = lane >> 4;
    const int st_r = lane >> 3;                // staging row within 8-row chunk
    const int st_s = (lane & 7) ^ st_r;        // XOR-swizzled source slice

    if (tid < TMB) {
        lab_s[tid]  = labels[row0 + tid];
        slab_s[tid] = 0.0f;
    }

    // A fragments direct from global: af[mi][kc][kk] = e[rowA, kc*64+kk*32+q*8 ..+8]
    bf16x8 af[4][4][2];
    #pragma unroll
    for (int mi = 0; mi < 4; ++mi) {
        const unsigned short* pa =
            e + (size_t)(row0 + wm*64 + mi*16 + l16) * DIM + q * 8;
        #pragma unroll
        for (int kc = 0; kc < 4; ++kc)
            #pragma unroll
            for (int kk = 0; kk < 2; ++kk)
                af[mi][kc][kk] = *(const bf16x8*)(pa + kc*64 + kk*32);
    }

    auto stageB = [&](int cb_, int kc_, int buf_) {
        #pragma unroll
        for (int ch = 0; ch < 4; ++ch) {
            int chunk = wave * 4 + ch;          // 16 chunks of 8 class-rows
            int row   = chunk * 8 + st_r;
            gload_lds16(&cs[(size_t)(cb_ * TCB + row) * DIM + kc_ * 64 + st_s * 8],
                        &b_s[buf_][chunk * 512]);
        }
    };

    float negp[4][4];
    #pragma unroll
    for (int mi = 0; mi < 4; ++mi)
        #pragma unroll
        for (int rg = 0; rg < 4; ++rg) negp[mi][rg] = 0.0f;

    stageB(0, 0, 0);

    for (int cb = 0; cb < CPAD / TCB; ++cb) {
        f32x4 accf[4][4] = {};
        #pragma unroll
        for (int kc = 0; kc < 4; ++kc) {
            int t = cb * 4 + kc;
            __syncthreads();                    // drains glds(t); buf reuse safe
            if (t < 31) stageB((t + 1) >> 2, (t + 1) & 3, (t + 1) & 1);
            const unsigned short* bs = b_s[t & 1];
            #pragma unroll
            for (int kk = 0; kk < 2; ++kk) {
                bf16x8 bfr[4];
                #pragma unroll
                for (int ni = 0; ni < 4; ++ni) {
                    int rowB = wn*64 + ni*16 + l16;
                    bfr[ni] = *(const bf16x8*)&bs[rowB*64 + (((kk*4 + q) ^ (rowB & 7)) * 8)];
                }
                #pragma unroll
                for (int mi = 0; mi < 4; ++mi)
                    #pragma unroll
                    for (int ni = 0; ni < 4; ++ni)
                        accf[mi][ni] = __builtin_amdgcn_mfma_f32_16x16x32_bf16(
                            af[mi][kc][kk], bfr[ni], accf[mi][ni], 0, 0, 0);
            }
        }
        // epilogue for this class tile: C/D col = l16, row = q*4 + reg
        // (overlaps with next tile's glds already in flight)
        #pragma unroll
        for (int mi = 0; mi < 4; ++mi) {
            #pragma unroll
            for (int rg = 0; rg < 4; ++rg) {
                int rloc = wm*64 + mi*16 + q*4 + rg;
                int lab  = lab_s[rloc];
                #pragma unroll
                for (int ni = 0; ni < 4; ++ni) {
                    int c   = cb * TCB + wn*64 + ni*16 + l16;
                    float s = accf[mi][ni][rg];
                    if (c < NCLS) {
                        float t2 = fmaxf(1.0f - s, 0.0f);
                        negp[mi][rg] += t2 * t2;
                        if (c == lab) slab_s[rloc] = s;   // unique writer per row
                    }
                }
            }
        }
    }

    #pragma unroll
    for (int mi = 0; mi < 4; ++mi) {
        #pragma unroll
        for (int rg = 0; rg < 4; ++rg) {
            float v = negp[mi][rg];
            #pragma unroll
            for (int off = 8; off >= 1; off >>= 1) v += __shfl_down(v, off, 16);
            if (l16 == 0) negsum_s[wn][wm*64 + mi*16 + q*4 + rg] = v;
        }
    }
    __syncthreads();

    float part = 0.0f;
    if (tid < TMB) {
        float ns = negsum_s[0][tid] + negsum_s[1][tid];
        float sl = slab_s[tid];
        float t  = fmaxf(1.0f - sl, 0.0f);
        part = (sl - 1.0f) * (sl - 1.0f) + (ns - t * t) * (1.0f / 999.0f);
    }
    #pragma unroll
    for (int off = 32; off >= 1; off >>= 1) part += __shfl_down(part, off, 64);
    if (lane == 0) red_s[wave] = part;
    __syncthreads();
    if (tid == 0) atomicAdd(acc, red_s[0] + red_s[1] + red_s[2] + red_s[3]);
}

__global__ void k_final(const float* __restrict__ acc, float* __restrict__ out)
{
    if (threadIdx.x == 0) out[0] = acc[0] * (1.0f / (float)NROWS);
}

extern "C" void kernel_launch(void* const* d_in, const int* in_sizes, int n_in,
                              void* d_out, int out_size, void* d_ws, size_t ws_size,
                              hipStream_t stream)
{
    const float* emb    = (const float*)d_in[0];
    const int*   labels = (const int*)d_in[1];
    float*       out    = (float*)d_out;
    char*        ws     = (char*)d_ws;

    const size_t OFF_SUMS = (size_t)NROWS * DIM * 2;            // e: 32 MB
    const size_t OFF_CNT  = OFF_SUMS + (size_t)NCLS * DIM * 4;  // sums: 1 MB
    const size_t OFF_ACC  = OFF_CNT + 4096;                     // counts: 4 KB
    const size_t OFF_OFFS = OFF_ACC + 16;                       // acc: 16 B
    const size_t OFF_CUR  = OFF_OFFS + 4096;                    // offs: 4 KB
    const size_t OFF_SIDX = OFF_CUR + 4096;                     // cursor: 4 KB
    const size_t OFF_CS   = OFF_SIDX + (size_t)NROWS * 4;       // sidx: 256 KB

    unsigned short* e      = (unsigned short*)ws;
    float*          sums   = (float*)(ws + OFF_SUMS);
    unsigned int*   counts = (unsigned int*)(ws + OFF_CNT);
    float*          acc    = (float*)(ws + OFF_ACC);
    unsigned int*   offs   = (unsigned int*)(ws + OFF_OFFS);
    unsigned int*   cursor = (unsigned int*)(ws + OFF_CUR);
    int*            sidx   = (int*)(ws + OFF_SIDX);
    unsigned short* cs     = (unsigned short*)(ws + OFF_CS);

    // zero counts + acc (contiguous); everything else is fully overwritten
    hipMemsetAsync(ws + OFF_CNT, 0, 4096 + 16, stream);

    k_norm_acc  <<<NROWS / 4, 256, 0, stream>>>(emb, labels, e, counts);
    k_prefix    <<<1, 1024, 0, stream>>>(counts, offs, cursor);
    k_scatter   <<<NROWS / 256, 256, 0, stream>>>(labels, cursor, sidx);
    k_gather_sum<<<NCLS, 256, 0, stream>>>(e, sidx, offs, counts, sums);
    k_centers   <<<CPAD / 4, 256, 0, stream>>>(sums, counts, cs);
    k_loss_mfma <<<NROWS / TMB, 256, 0, stream>>>(e, cs, labels, acc);
    k_final     <<<1, 64, 0, stream>>>(acc, out);
}